// Round 7
// baseline (19771.440 us; speedup 1.0000x reference)
//
#include <hip/hip_runtime.h>
#include <cstdint>
#include <cstddef>

typedef unsigned short u16;
typedef unsigned int   u32;
typedef unsigned long long u64;

#define S_LEN 100
#define B_SZ  512
#define H_LS  300
#define NHOP  3
#define NC_   7
#define BM1   511   // B-1

__device__ __forceinline__ float u2f(u16 u) {
  union { u32 i; float f; } x; x.i = ((u32)u) << 16; return x.f;
}
__device__ __forceinline__ float sigm(float x) { return 1.0f / (1.0f + expf(-x)); }

// ------------------------------------------------------------------
// dtype detect on emb raw bits (validated r1->r2: f32 detected => finite)
// ------------------------------------------------------------------
__global__ void detect_k(const u32* __restrict__ raw, int* __restrict__ flag) {
  __shared__ int cnt;
  if (threadIdx.x == 0) cnt = 0;
  __syncthreads();
  u32 w = raw[threadIdx.x];
  u32 lo = w & 0xFFFFu;
  int e = (int)((lo >> 7) & 0xFF);
  int pl = (lo == 0u || (e >= 0x70 && e <= 0x8E)) ? 1 : 0;
  atomicAdd(&cnt, pl);
  __syncthreads();
  if (threadIdx.x == 0) *flag = (cnt >= 192) ? 1 : 0;   // 1 = bf16 device data
}

// ------------------------------------------------------------------
// normalize ALL float params (incl. LSTM weights) -> f32 mirror allf
// ------------------------------------------------------------------
#define NF_NSEG 28
#define NF_TOT  1748007
struct NormFArgs { const void* src[NF_NSEG]; const int* flag; float* dst; };

__global__ __launch_bounds__(256) void norm_f32(NormFArgs a) {
  const int P[NF_NSEG + 1] = {
    0,360000,720000,1080000,1440000,1441200,1442400,1443600,
    1444800,1474800,1504800,1505100,1505400,1535400,1565400,1565700,
    1566000,1626000,1626100,1656100,1686100,1716100,1746100,1746400,
    1746700,1747000,1747300,1748000,1748007};
  int fl = *a.flag;
  int stride = gridDim.x * 256;
  for (int i = blockIdx.x * 256 + threadIdx.x; i < NF_TOT; i += stride) {
    int s = 0;
    while (i >= P[s + 1]) ++s;
    int k = i - P[s];
    float v = fl ? u2f(((const u16*)a.src[s])[k]) : ((const float*)a.src[s])[k];
    a.dst[i] = v;
  }
}
// allf element offsets
#define AF_LWIH_F 0
#define AF_LWHH_F 360000
#define AF_LWIH_B 720000
#define AF_LWHH_B 1080000
#define AF_LBIH_F 1440000
#define AF_LBHH_F 1441200
#define AF_LBIH_B 1442400
#define AF_LBHH_B 1443600
#define AF_GWIH_F 1444800
#define AF_GWHH_F 1474800
#define AF_GBIH_F 1504800
#define AF_GBHH_F 1505100
#define AF_GWIH_B 1505400
#define AF_GWHH_B 1535400
#define AF_GBIH_B 1565400
#define AF_GBHH_B 1565700
#define AF_LIN1W  1566000
#define AF_LIN1B  1626000
#define AF_ATTWR  1626100
#define AF_ATTUR  1656100
#define AF_ATTW   1686100
#define AF_ATTU   1716100
#define AF_ATTBR  1746100
#define AF_ATTBUR 1746400
#define AF_ATTBW  1746700
#define AF_ATTBU  1747000
#define AF_CLSW   1747300
#define AF_CLSB   1748000

// ------------------------------------------------------------------
// LSTM step, simplest-possible f32 form. Grid (32,25,2), 256 thr.
// Block: 16 batch rows x 12 h-dims. Thread (tid<192) owns ONE (row,j):
// computes all 4 gates itself then the cell update. K_x = 300 (D_EMB),
// K_h = 300. Wih row (g*300+j): offset g*90000 + j*300 (row len 300).
// ------------------------------------------------------------------
struct Lstm2Args {
  const int* sents; const int* lens;
  const void* emb;                       // original, dtype per flag
  const float* Wih[2]; const float* Whh[2];
  const float* bih[2]; const float* bhh[2];
  const int* flag;
  float* h;      // [parity][dir][512][300] f32
  float* c;      // [dir][512][300] f32
  float* maxb;   // [512][600]
  int s;
};

__global__ __launch_bounds__(256) void lstm2(Lstm2Args a) {
  __shared__ float xe[16][304];   // emb rows (300 f32)
  __shared__ float xh[16][304];   // h_{t-1} rows
  const int tid = threadIdx.x;
  const int r0  = blockIdx.x * 16;
  const int j0  = blockIdx.y * 12;
  const int dir = blockIdx.z;
  const int s   = a.s;
  const int tt  = dir ? (S_LEN - 1 - s) : s;
  const int rp  = s & 1;
  const float* hread  = a.h + (size_t)(rp * 2 + dir) * B_SZ * H_LS;
  float*       hwrite = a.h + (size_t)((1 - rp) * 2 + dir) * B_SZ * H_LS;
  const int fl = *a.flag;

  for (int idx = tid; idx < 16 * 300; idx += 256) {
    int r = idx / 300, k = idx - r * 300;
    int tok = a.sents[(r0 + r) * S_LEN + tt];
    float v = fl ? u2f(((const u16*)a.emb)[(size_t)tok * 300 + k])
                 : ((const float*)a.emb)[(size_t)tok * 300 + k];
    xe[r][k] = v;
    xh[r][k] = (s > 0) ? hread[(size_t)(r0 + r) * H_LS + k] : 0.f;
  }
  __syncthreads();

  if (tid < 192) {
    const int row = tid & 15;
    const int jj  = tid >> 4;     // 0..11
    const int b   = r0 + row;
    const int j   = j0 + jj;
    const float* bihd = a.bih[dir];
    const float* bhhd = a.bhh[dir];
    float gi = bihd[j]       + bhhd[j];
    float gf = bihd[300 + j] + bhhd[300 + j];
    float gg = bihd[600 + j] + bhhd[600 + j];
    float go = bihd[900 + j] + bhhd[900 + j];
    const float* wi = a.Wih[dir] + (size_t)j * 300;   // + g*90000
    const float* wh = a.Whh[dir] + (size_t)j * 300;
    for (int k = 0; k < 300; ++k) {
      float x = xe[row][k];
      gi += x * wi[k];
      gf += x * wi[k + 90000];
      gg += x * wi[k + 180000];
      go += x * wi[k + 270000];
    }
    for (int k = 0; k < 300; ++k) {
      float x = xh[row][k];
      gi += x * wh[k];
      gf += x * wh[k + 90000];
      gg += x * wh[k + 180000];
      go += x * wh[k + 270000];
    }
    bool m = tt < a.lens[b];
    size_t cix = ((size_t)dir * B_SZ + b) * H_LS + j;
    size_t hix = (size_t)b * H_LS + j;
    float outv = 0.f;
    if (m) {
      float cp = (s == 0) ? 0.f : a.c[cix];
      float cn = sigm(gf) * cp + sigm(gi) * tanhf(gg);
      float hn = sigm(go) * tanhf(cn);
      a.c[cix] = cn;
      hwrite[hix] = hn;
      outv = hn;
    } else {
      if (s == 0) { a.c[cix] = 0.f; hwrite[hix] = 0.f; }
      else hwrite[hix] = xh[row][j];
    }
    size_t mix = (size_t)b * 600 + dir * 300 + j;
    a.maxb[mix] = (s == 0) ? outv : fmaxf(a.maxb[mix], outv);
  }
}

// ------------------------------------------------------------------
// s_utt = tanh(maxpl @ lin1_W^T + lin1_b)   [512,100]; lin1_W is [100][600]
// ------------------------------------------------------------------
__global__ __launch_bounds__(128) void sutt_k(const float* __restrict__ maxb,
                                              const float* __restrict__ W,
                                              const float* __restrict__ bb,
                                              float* __restrict__ sutt) {
  int b = blockIdx.x, tid = threadIdx.x;
  __shared__ float mx[600];
  for (int i = tid; i < 600; i += 128) mx[i] = maxb[b * 600 + i];
  __syncthreads();
  if (tid < 100) {
    float acc = bb[tid];
    const float* wr = W + tid * 600;
    for (int k = 0; k < 600; ++k) acc += mx[k] * wr[k];
    sutt[b * 100 + tid] = tanhf(acc);
  }
}

// ------------------------------------------------------------------
// Bi-GRU scan, xg computed inline. Block owns 8 rows; grid (64,2).
// ------------------------------------------------------------------
struct Gru2Args {
  const float* Whh[2]; const float* bhh[2];
  const float* Wih[2]; const float* bih[2];
  const float* sutt; float* memf; float* memb;
};

__global__ __launch_bounds__(256) void gru2(Gru2Args a) {
  __shared__ float hl[8][104];
  int tid = threadIdx.x, rt = blockIdx.x * 8, dir = blockIdx.y;
  const float* Whh = a.Whh[dir]; const float* bhh = a.bhh[dir];
  const float* Wih = a.Wih[dir]; const float* bih = a.bih[dir];
  for (int i = tid; i < 800; i += 256) hl[i / 100][i % 100] = 0.f;
  __syncthreads();
  for (int t = 0; t < 40; ++t) {
    int tin = dir ? (39 - t) : t;
    float nh[4]; int cnt = 0;
    for (int it = tid; it < 800; it += 256, ++cnt) {
      int r = it / 100, j = it % 100, row = rt + r;
      float v = 0.f;
      if (row < BM1) {
        float xr = bih[j], xz = bih[100 + j], xn = bih[200 + j];
        int srow = row + 1 - 40 + tin;
        if (srow >= 0) {
          const float* bp = a.sutt + srow * 100;
          const float* w0 = Wih + j * 100;
          for (int k = 0; k < 100; ++k) {
            float bv = bp[k];
            xr += bv * w0[k];
            xz += bv * w0[k + 10000];
            xn += bv * w0[k + 20000];
          }
        }
        float hr = bhh[j], hz = bhh[100 + j], hn = bhh[200 + j];
        const float* v0 = Whh + j * 100;
        for (int k = 0; k < 100; ++k) {
          float hv = hl[r][k];
          hr += hv * v0[k];
          hz += hv * v0[k + 10000];
          hn += hv * v0[k + 20000];
        }
        float rg = sigm(xr + hr), zg = sigm(xz + hz);
        float ng = tanhf(xn + rg * hn);
        v = (1.f - zg) * ng + zg * hl[r][j];
        size_t ot = ((size_t)tin * BM1 + row) * 100 + j;   // dir0: tin==t
        (dir ? a.memb : a.memf)[ot] = v;
      }
      nh[cnt] = v;
    }
    __syncthreads();
    cnt = 0;
    for (int it = tid; it < 800; it += 256, ++cnt) hl[it / 100][it % 100] = nh[cnt];
    __syncthreads();
  }
}

// mem = bt + mem_f + mem_b   [40][511][100]
__global__ void memcomb(const float* __restrict__ memf, const float* __restrict__ memb,
                        const float* __restrict__ sutt, float* __restrict__ memm) {
  int idx = blockIdx.x * 256 + threadIdx.x;
  if (idx >= 40 * BM1 * 100) return;
  int j = idx % 100; int rem = idx / 100; int row = rem % BM1; int t = rem / BM1;
  float v = memf[idx] + memb[idx];
  int sidx = row + 1 - 40 + t;
  if (sidx >= 0) v += sutt[sidx * 100 + j];
  memm[idx] = v;
}

__global__ void epsinit(const float* __restrict__ sutt, float* __restrict__ eps) {
  int idx = blockIdx.x * 256 + threadIdx.x;
  if (idx < BM1 * 100) eps[idx] = sutt[idx + 100];
}

// attention scores + softmax -> gates (f32) + attn output (f32!)
__global__ __launch_bounds__(64) void attnsc(const float* __restrict__ eps,
                                             const float* __restrict__ memm,
                                             float* __restrict__ gatesw,
                                             float* __restrict__ outat) {
  int row = blockIdx.x, k = threadIdx.x;
  __shared__ float el[100];
  for (int i = k; i < 100; i += 64) el[i] = eps[row * 100 + i];
  __syncthreads();
  float val = -INFINITY;
  if (k < 40) {
    if (row + 1 - 40 + k >= 0) {
      const float* mrow = memm + ((size_t)k * BM1 + row) * 100;
      float s = 0.f;
      for (int d = 0; d < 100; ++d) s += el[d] * mrow[d];
      val = s;
    } else val = -1e10f;
  }
  float mx = val;
  for (int off = 32; off > 0; off >>= 1) mx = fmaxf(mx, __shfl_xor(mx, off));
  float ex = (k < 40) ? expf(val - mx) : 0.f;
  float sm = ex;
  for (int off = 32; off > 0; off >>= 1) sm += __shfl_xor(sm, off);
  if (k < 40) {
    float sc = ex / sm;
    gatesw[k * BM1 + row] = sc;
    outat[row * 40 + k] = sc;
  }
}

// ------------------------------------------------------------------
// AttnGRU scan (one hop), cr/cw computed inline. eps += h at end.
// ------------------------------------------------------------------
struct Att2Args {
  const float* Ur; const float* bur; const float* U;  const float* bu;
  const float* Wr; const float* br;  const float* W;  const float* bw;
  const float* gatesw; const float* memm; float* eps;
};

__global__ __launch_bounds__(256) void attngru2(Att2Args a) {
  __shared__ float hl[8][104];
  int tid = threadIdx.x, rt = blockIdx.x * 8;
  for (int i = tid; i < 800; i += 256) hl[i / 100][i % 100] = 0.f;
  __syncthreads();
  for (int t = 0; t < 40; ++t) {
    float nh[4]; int cnt = 0;
    for (int it = tid; it < 800; it += 256, ++cnt) {
      int r = it / 100, j = it % 100, row = rt + r;
      float v = 0.f;
      if (row < BM1) {
        const float* mrow = a.memm + ((size_t)t * BM1 + row) * 100;
        float crt = a.br[j], cwt = a.bw[j];
        const float* wr = a.Wr + j * 100;
        const float* ww = a.W  + j * 100;
        for (int k = 0; k < 100; ++k) {
          float mv = mrow[k];
          crt += mv * wr[k];
          cwt += mv * ww[k];
        }
        float hr = a.bur[j], hu = a.bu[j];
        const float* ur = a.Ur + j * 100;
        const float* uu = a.U  + j * 100;
        for (int k = 0; k < 100; ++k) {
          float hv = hl[r][k];
          hr += hv * ur[k];
          hu += hv * uu[k];
        }
        float g  = a.gatesw[t * BM1 + row];
        float rg = sigm(crt + hr);
        float ht = tanhf(cwt + rg * hu);
        v = g * ht + (1.f - g) * hl[r][j];
      }
      nh[cnt] = v;
    }
    __syncthreads();
    cnt = 0;
    for (int it = tid; it < 800; it += 256, ++cnt) hl[it / 100][it % 100] = nh[cnt];
    __syncthreads();
  }
  for (int it = tid; it < 800; it += 256) {
    int r = it / 100, j = it % 100, row = rt + r;
    if (row < BM1) a.eps[row * 100 + j] += hl[r][j];
  }
}

// classifier: log_softmax(s_cont @ cls_W^T + cls_b) -> f32
__global__ __launch_bounds__(64) void cls_k(const float* __restrict__ sutt,
                                            const float* __restrict__ eps,
                                            const float* __restrict__ cW, const float* __restrict__ cb,
                                            float* __restrict__ outp) {
  int b = blockIdx.x, j = threadIdx.x;
  __shared__ float sl[100];
  for (int i = j; i < 100; i += 64) sl[i] = (b == 0) ? sutt[i] : eps[(b - 1) * 100 + i];
  __syncthreads();
  float lg = -INFINITY;
  if (j < 7) {
    lg = cb[j];
    const float* wr = cW + j * 100;
    for (int k = 0; k < 100; ++k) lg += sl[k] * wr[k];
  }
  float mx = lg;
  for (int off = 32; off > 0; off >>= 1) mx = fmaxf(mx, __shfl_xor(mx, off));
  float ex = (j < 7) ? expf(lg - mx) : 0.f;
  float sm = ex;
  for (int off = 32; off > 0; off >>= 1) sm += __shfl_xor(sm, off);
  if (j < 7) outp[b * 7 + j] = lg - mx - logf(sm);
}

// ------------------------------------------------------------------
extern "C" void kernel_launch(void* const* d_in, const int* in_sizes, int n_in,
                              void* d_out, int out_size, void* d_ws, size_t ws_size,
                              hipStream_t stream) {
  (void)n_in; (void)out_size; (void)ws_size;

  // input-order detection (r4 evidence: dict order; keep branch for safety)
  bool sigOrder = (in_sizes[7] == 360000);

  const void *p_sents, *p_lens, *p_emb;
  const void *p_lWih_f, *p_lWhh_f, *p_lbih_f, *p_lbhh_f;
  const void *p_lWih_b, *p_lWhh_b, *p_lbih_b, *p_lbhh_b;
  const void *p_gWih_f, *p_gWhh_f, *p_gbih_f, *p_gbhh_f;
  const void *p_gWih_b, *p_gWhh_b, *p_gbih_b, *p_gbhh_b;
  const void *p_lin1W, *p_lin1b;
  const void *p_attWr, *p_attUr, *p_attW, *p_attU;
  const void *p_attbr, *p_attbur, *p_attbw, *p_attbu;
  const void *p_clsW, *p_clsb;

  p_sents = d_in[0]; p_lens = d_in[1]; p_emb = d_in[2];
  p_lWih_f = d_in[3]; p_lWhh_f = d_in[4]; p_lbih_f = d_in[5]; p_lbhh_f = d_in[6];
  if (sigOrder) {
    p_lWih_b = d_in[7];  p_lWhh_b = d_in[8];  p_lbih_b = d_in[9];  p_lbhh_b = d_in[10];
    p_lin1W  = d_in[11]; p_lin1b  = d_in[12];
    p_gWih_f = d_in[13]; p_gWhh_f = d_in[14]; p_gbih_f = d_in[15]; p_gbhh_f = d_in[16];
    p_gWih_b = d_in[17]; p_gWhh_b = d_in[18]; p_gbih_b = d_in[19]; p_gbhh_b = d_in[20];
    p_attWr  = d_in[21]; p_attbr  = d_in[22]; p_attUr  = d_in[23]; p_attbur = d_in[24];
    p_attW   = d_in[25]; p_attbw  = d_in[26]; p_attU   = d_in[27]; p_attbu  = d_in[28];
    p_clsW   = d_in[29]; p_clsb   = d_in[30];
  } else {
    p_gWih_f = d_in[7];  p_gWhh_f = d_in[8];  p_gbih_f = d_in[9];  p_gbhh_f = d_in[10];
    p_lWih_b = d_in[11]; p_lWhh_b = d_in[12]; p_lbih_b = d_in[13]; p_lbhh_b = d_in[14];
    p_gWih_b = d_in[15]; p_gWhh_b = d_in[16]; p_gbih_b = d_in[17]; p_gbhh_b = d_in[18];
    p_lin1W  = d_in[19]; p_lin1b  = d_in[20];
    p_attWr  = d_in[21]; p_attUr  = d_in[22]; p_attW   = d_in[23]; p_attU   = d_in[24];
    p_attbr  = d_in[25]; p_attbur = d_in[26]; p_attbw  = d_in[27]; p_attbu  = d_in[28];
    p_clsW   = d_in[29]; p_clsb   = d_in[30];
  }

  char* wp = (char*)d_ws;
  auto carve = [&](size_t bytes) {
    char* p = wp;
    wp += (bytes + 255) & ~(size_t)255;
    return p;
  };
  int*   flag  = (int*)  carve(256);
  float* allf  = (float*)carve((size_t)NF_TOT * 4);
  float* hbuf  = (float*)carve((size_t)2 * 2 * B_SZ * H_LS * 4);
  float* cst   = (float*)carve((size_t)2 * B_SZ * H_LS * 4);
  float* maxb  = (float*)carve((size_t)B_SZ * 600 * 4);
  float* sutt  = (float*)carve((size_t)B_SZ * 100 * 4);
  float* memf  = (float*)carve((size_t)40 * BM1 * 100 * 4);
  float* memb  = (float*)carve((size_t)40 * BM1 * 100 * 4);
  float* memm  = (float*)carve((size_t)40 * BM1 * 100 * 4);
  float* gatesw= (float*)carve((size_t)40 * BM1 * 4);
  float* eps   = (float*)carve((size_t)BM1 * 100 * 4);

  float* out_pred = (float*)d_out;               // f32 output! (r6 post-mortem)
  float* out_attn = out_pred + (size_t)B_SZ * NC_;

  detect_k<<<1, 256, 0, stream>>>((const u32*)p_emb, flag);

  NormFArgs nf;
  {
    const void* srcs[NF_NSEG] = {
      p_lWih_f, p_lWhh_f, p_lWih_b, p_lWhh_b,
      p_lbih_f, p_lbhh_f, p_lbih_b, p_lbhh_b,
      p_gWih_f, p_gWhh_f, p_gbih_f, p_gbhh_f,
      p_gWih_b, p_gWhh_b, p_gbih_b, p_gbhh_b,
      p_lin1W,  p_lin1b,
      p_attWr,  p_attUr,  p_attW,   p_attU,
      p_attbr,  p_attbur, p_attbw,  p_attbu,
      p_clsW,   p_clsb };
    for (int i = 0; i < NF_NSEG; ++i) nf.src[i] = srcs[i];
    nf.flag = flag; nf.dst = allf;
  }
  norm_f32<<<2048, 256, 0, stream>>>(nf);

  Lstm2Args la;
  la.sents = (const int*)p_sents; la.lens = (const int*)p_lens;
  la.emb = p_emb;
  la.Wih[0] = allf + AF_LWIH_F; la.Wih[1] = allf + AF_LWIH_B;
  la.Whh[0] = allf + AF_LWHH_F; la.Whh[1] = allf + AF_LWHH_B;
  la.bih[0] = allf + AF_LBIH_F; la.bih[1] = allf + AF_LBIH_B;
  la.bhh[0] = allf + AF_LBHH_F; la.bhh[1] = allf + AF_LBHH_B;
  la.flag = flag;
  la.h = hbuf; la.c = cst; la.maxb = maxb;
  for (int s = 0; s < S_LEN; ++s) {
    la.s = s;
    lstm2<<<dim3(32, 25, 2), 256, 0, stream>>>(la);
  }

  sutt_k<<<512, 128, 0, stream>>>(maxb, allf + AF_LIN1W, allf + AF_LIN1B, sutt);

  Gru2Args ga;
  ga.Whh[0] = allf + AF_GWHH_F; ga.Whh[1] = allf + AF_GWHH_B;
  ga.bhh[0] = allf + AF_GBHH_F; ga.bhh[1] = allf + AF_GBHH_B;
  ga.Wih[0] = allf + AF_GWIH_F; ga.Wih[1] = allf + AF_GWIH_B;
  ga.bih[0] = allf + AF_GBIH_F; ga.bih[1] = allf + AF_GBIH_B;
  ga.sutt = sutt; ga.memf = memf; ga.memb = memb;
  gru2<<<dim3(64, 2), 256, 0, stream>>>(ga);

  memcomb<<<(40 * BM1 * 100 + 255) / 256, 256, 0, stream>>>(memf, memb, sutt, memm);
  epsinit<<<(BM1 * 100 + 255) / 256, 256, 0, stream>>>(sutt, eps);

  for (int hop = 0; hop < NHOP; ++hop) {
    attnsc<<<BM1, 64, 0, stream>>>(eps, memm, gatesw, out_attn + (size_t)hop * BM1 * 40);
    Att2Args aa;
    aa.Ur = allf + AF_ATTUR + hop * 10000; aa.bur = allf + AF_ATTBUR + hop * 100;
    aa.U  = allf + AF_ATTU  + hop * 10000; aa.bu  = allf + AF_ATTBU  + hop * 100;
    aa.Wr = allf + AF_ATTWR + hop * 10000; aa.br  = allf + AF_ATTBR  + hop * 100;
    aa.W  = allf + AF_ATTW  + hop * 10000; aa.bw  = allf + AF_ATTBW  + hop * 100;
    aa.gatesw = gatesw; aa.memm = memm; aa.eps = eps;
    attngru2<<<64, 256, 0, stream>>>(aa);
  }

  cls_k<<<512, 64, 0, stream>>>(sutt, eps, allf + AF_CLSW, allf + AF_CLSB, out_pred);
}

// Round 8
// 12604.917 us; speedup vs baseline: 1.5685x; 1.5685x over previous
//
#include <hip/hip_runtime.h>
#include <cstdint>
#include <cstddef>

typedef unsigned short u16;
typedef unsigned int   u32;

#define S_LEN 100
#define B_SZ  512
#define H_LS  300
#define NHOP  3
#define NC_   7
#define BM1   511   // B-1

__device__ __forceinline__ float u2f(u16 u) {
  union { u32 i; float f; } x; x.i = ((u32)u) << 16; return x.f;
}
__device__ __forceinline__ float sigm(float x) { return 1.0f / (1.0f + expf(-x)); }

// ------------------------------------------------------------------
// dtype detect on emb raw bits (validated r1->r2)
// ------------------------------------------------------------------
__global__ void detect_k(const u32* __restrict__ raw, int* __restrict__ flag) {
  __shared__ int cnt;
  if (threadIdx.x == 0) cnt = 0;
  __syncthreads();
  u32 w = raw[threadIdx.x];
  u32 lo = w & 0xFFFFu;
  int e = (int)((lo >> 7) & 0xFF);
  int pl = (lo == 0u || (e >= 0x70 && e <= 0x8E)) ? 1 : 0;
  atomicAdd(&cnt, pl);
  __syncthreads();
  if (threadIdx.x == 0) *flag = (cnt >= 192) ? 1 : 0;   // 1 = bf16 device data
}

// ------------------------------------------------------------------
// normalize ALL float params -> f32 mirror allf (validated r6/r7)
// ------------------------------------------------------------------
#define NF_NSEG 28
#define NF_TOT  1748007
struct NormFArgs { const void* src[NF_NSEG]; const int* flag; float* dst; };

__global__ __launch_bounds__(256) void norm_f32(NormFArgs a) {
  const int P[NF_NSEG + 1] = {
    0,360000,720000,1080000,1440000,1441200,1442400,1443600,
    1444800,1474800,1504800,1505100,1505400,1535400,1565400,1565700,
    1566000,1626000,1626100,1656100,1686100,1716100,1746100,1746400,
    1746700,1747000,1747300,1748000,1748007};
  int fl = *a.flag;
  int stride = gridDim.x * 256;
  for (int i = blockIdx.x * 256 + threadIdx.x; i < NF_TOT; i += stride) {
    int s = 0;
    while (i >= P[s + 1]) ++s;
    int k = i - P[s];
    float v = fl ? u2f(((const u16*)a.src[s])[k]) : ((const float*)a.src[s])[k];
    a.dst[i] = v;
  }
}
#define AF_LWIH_F 0
#define AF_LWHH_F 360000
#define AF_LWIH_B 720000
#define AF_LWHH_B 1080000
#define AF_LBIH_F 1440000
#define AF_LBHH_F 1441200
#define AF_LBIH_B 1442400
#define AF_LBHH_B 1443600
#define AF_GWIH_F 1444800
#define AF_GWHH_F 1474800
#define AF_GBIH_F 1504800
#define AF_GBHH_F 1505100
#define AF_GWIH_B 1505400
#define AF_GWHH_B 1535400
#define AF_GBIH_B 1565400
#define AF_GBHH_B 1565700
#define AF_LIN1W  1566000
#define AF_LIN1B  1626000
#define AF_ATTWR  1626100
#define AF_ATTUR  1656100
#define AF_ATTW   1686100
#define AF_ATTU   1716100
#define AF_ATTBR  1746100
#define AF_ATTBUR 1746400
#define AF_ATTBW  1746700
#define AF_ATTBU  1747000
#define AF_CLSW   1747300
#define AF_CLSB   1748000

// ------------------------------------------------------------------
// transpose 100x100 chunks to k-major: gWhh (2 dirs x 3 gates) + att Ur/U
// wt layout: [0..30000) gWhhT_f | [30000..60000) gWhhT_b
//            [60000..90000) UrT hops | [90000..120000) UT hops
// ------------------------------------------------------------------
__global__ void transp_k(const float* __restrict__ allf, float* __restrict__ wt) {
  int idx = blockIdx.x * 256 + threadIdx.x;
  if (idx >= 120000) return;
  int seg = idx / 10000;
  int rem = idx - seg * 10000;
  int k = rem / 100, j = rem - (rem / 100) * 100;
  int srcbase;
  if (seg < 3)      srcbase = AF_GWHH_F + seg * 10000;
  else if (seg < 6) srcbase = AF_GWHH_B + (seg - 3) * 10000;
  else if (seg < 9) srcbase = AF_ATTUR + (seg - 6) * 10000;
  else              srcbase = AF_ATTU  + (seg - 9) * 10000;
  wt[seg * 10000 + k * 100 + j] = allf[srcbase + j * 100 + k];
}

// ------------------------------------------------------------------
// LSTM step v3: grid (16 rowt[32], 10 jt[30], 2 dir), 256 thr (240 active).
// Thread owns (1 j, 4 rows): float4 weight loads feed 16 FMAs each.
// x/h staged in LDS (broadcast reads across row-groups).
// ------------------------------------------------------------------
struct Lstm3Args {
  const int* sents; const int* lens;
  const void* emb;
  const float* Wih[2]; const float* Whh[2];
  const float* bih[2]; const float* bhh[2];
  const int* flag;
  float* h;      // [parity][dir][512][300]
  float* c;      // [dir][512][300]
  float* maxb;   // [512][600]
  int s;
};

__global__ __launch_bounds__(256) void lstm3(Lstm3Args a) {
  __shared__ float xe[32][304];
  __shared__ float xh[32][304];
  const int tid = threadIdx.x;
  const int r0  = blockIdx.x * 32;
  const int j0  = blockIdx.y * 30;
  const int dir = blockIdx.z;
  const int s   = a.s;
  const int tt  = dir ? (S_LEN - 1 - s) : s;
  const int rp  = s & 1;
  const float* hread  = a.h + (size_t)(rp * 2 + dir) * B_SZ * H_LS;
  float*       hwrite = a.h + (size_t)((1 - rp) * 2 + dir) * B_SZ * H_LS;
  const int fl = *a.flag;

  for (int idx = tid; idx < 32 * 300; idx += 256) {
    int r = idx / 300, k = idx - r * 300;
    int tok = a.sents[(r0 + r) * S_LEN + tt];
    xe[r][k] = fl ? u2f(((const u16*)a.emb)[(size_t)tok * 300 + k])
                  : ((const float*)a.emb)[(size_t)tok * 300 + k];
    xh[r][k] = (s > 0) ? hread[(size_t)(r0 + r) * H_LS + k] : 0.f;
  }
  __syncthreads();

  if (tid < 240) {
    const int j  = tid % 30;
    const int rg = tid / 30;           // 0..7
    const int jd = j0 + j;
    float acc[4][4];
    #pragma unroll
    for (int rr = 0; rr < 4; ++rr)
      #pragma unroll
      for (int g = 0; g < 4; ++g) acc[rr][g] = 0.f;

    const float* wiB = a.Wih[dir] + (size_t)jd * 300;
    for (int k = 0; k < 300; k += 4) {
      float4 w0 = *(const float4*)(wiB + k);
      float4 w1 = *(const float4*)(wiB + 90000 + k);
      float4 w2 = *(const float4*)(wiB + 180000 + k);
      float4 w3 = *(const float4*)(wiB + 270000 + k);
      #pragma unroll
      for (int rr = 0; rr < 4; ++rr) {
        float4 xv = *(const float4*)&xe[rg * 4 + rr][k];
        acc[rr][0] += xv.x * w0.x + xv.y * w0.y + xv.z * w0.z + xv.w * w0.w;
        acc[rr][1] += xv.x * w1.x + xv.y * w1.y + xv.z * w1.z + xv.w * w1.w;
        acc[rr][2] += xv.x * w2.x + xv.y * w2.y + xv.z * w2.z + xv.w * w2.w;
        acc[rr][3] += xv.x * w3.x + xv.y * w3.y + xv.z * w3.z + xv.w * w3.w;
      }
    }
    const float* whB = a.Whh[dir] + (size_t)jd * 300;
    for (int k = 0; k < 300; k += 4) {
      float4 w0 = *(const float4*)(whB + k);
      float4 w1 = *(const float4*)(whB + 90000 + k);
      float4 w2 = *(const float4*)(whB + 180000 + k);
      float4 w3 = *(const float4*)(whB + 270000 + k);
      #pragma unroll
      for (int rr = 0; rr < 4; ++rr) {
        float4 xv = *(const float4*)&xh[rg * 4 + rr][k];
        acc[rr][0] += xv.x * w0.x + xv.y * w0.y + xv.z * w0.z + xv.w * w0.w;
        acc[rr][1] += xv.x * w1.x + xv.y * w1.y + xv.z * w1.z + xv.w * w1.w;
        acc[rr][2] += xv.x * w2.x + xv.y * w2.y + xv.z * w2.z + xv.w * w2.w;
        acc[rr][3] += xv.x * w3.x + xv.y * w3.y + xv.z * w3.z + xv.w * w3.w;
      }
    }

    const float* bihd = a.bih[dir];
    const float* bhhd = a.bhh[dir];
    const float bi = bihd[jd]       + bhhd[jd];
    const float bf = bihd[300 + jd] + bhhd[300 + jd];
    const float bg = bihd[600 + jd] + bhhd[600 + jd];
    const float bo = bihd[900 + jd] + bhhd[900 + jd];

    #pragma unroll
    for (int rr = 0; rr < 4; ++rr) {
      int row = rg * 4 + rr;
      int b = r0 + row;
      float gi = acc[rr][0] + bi;
      float gf = acc[rr][1] + bf;
      float gg = acc[rr][2] + bg;
      float go = acc[rr][3] + bo;
      bool m = tt < a.lens[b];
      size_t cix = ((size_t)dir * B_SZ + b) * H_LS + jd;
      size_t hix = (size_t)b * H_LS + jd;
      float outv = 0.f;
      if (m) {
        float cp = (s == 0) ? 0.f : a.c[cix];
        float cn = sigm(gf) * cp + sigm(gi) * tanhf(gg);
        float hn = sigm(go) * tanhf(cn);
        a.c[cix] = cn;
        hwrite[hix] = hn;
        outv = hn;
      } else {
        if (s == 0) { a.c[cix] = 0.f; hwrite[hix] = 0.f; }
        else hwrite[hix] = xh[row][jd];
      }
      size_t mix = (size_t)b * 600 + dir * 300 + jd;
      a.maxb[mix] = (s == 0) ? outv : fmaxf(a.maxb[mix], outv);
    }
  }
}

// ------------------------------------------------------------------
// s_utt = tanh(maxpl @ lin1_W^T + lin1_b)   [512,100]
// ------------------------------------------------------------------
__global__ __launch_bounds__(128) void sutt_k(const float* __restrict__ maxb,
                                              const float* __restrict__ W,
                                              const float* __restrict__ bb,
                                              float* __restrict__ sutt) {
  int b = blockIdx.x, tid = threadIdx.x;
  __shared__ float mx[600];
  for (int i = tid; i < 600; i += 128) mx[i] = maxb[b * 600 + i];
  __syncthreads();
  if (tid < 100) {
    float acc = bb[tid];
    const float* wr = W + tid * 600;
    for (int k = 0; k < 600; ++k) acc += mx[k] * wr[k];
    sutt[b * 100 + tid] = tanhf(acc);
  }
}

// ------------------------------------------------------------------
// GRU x-projection precompute: xg[dir][t][row][300] f32 (incl. bih)
// ------------------------------------------------------------------
__global__ __launch_bounds__(256) void gxg3(const float* __restrict__ sutt,
                                            const float* __restrict__ Wf, const float* __restrict__ bf_,
                                            const float* __restrict__ Wb, const float* __restrict__ bb_,
                                            float* __restrict__ xg) {
  __shared__ float bts[32][101];
  int tid = threadIdx.x;
  int rt = blockIdx.x * 32, t = blockIdx.y, dir = blockIdx.z;
  int tin = dir ? (39 - t) : t;
  for (int idx = tid; idx < 3200; idx += 256) {
    int r = idx / 100, k = idx - r * 100, row = rt + r;
    float v = 0.f;
    if (row < BM1) {
      int srow = row + 1 - 40 + tin;
      if (srow >= 0) v = sutt[srow * 100 + k];
    }
    bts[r][k] = v;
  }
  __syncthreads();
  const float* Wm = dir ? Wb : Wf;
  const float* bm = dir ? bb_ : bf_;
  for (int o = tid; o < 9600; o += 256) {
    int r = o & 31, g = o >> 5;
    float acc = bm[g];
    const float* wr = Wm + g * 100;
    const float* br = bts[r];
    for (int k = 0; k < 100; ++k) acc += br[k] * wr[k];
    int row = rt + r;
    if (row < BM1) xg[(((size_t)dir * 40 + t) * BM1 + row) * 300 + g] = acc;
  }
}

// ------------------------------------------------------------------
// GRU scan v3: block = 4 rows, grid (128, 2); WhhT (k-major) in LDS.
// ------------------------------------------------------------------
struct Gru3Args {
  const float* wt;          // gWhhT at + dir*30000
  const float* bhh[2];
  const float* xg;
  float* memf; float* memb;
};

__global__ __launch_bounds__(256) void gru3(Gru3Args a) {
  __shared__ float WT[30000];    // [3][100 k][100 j]
  __shared__ float hl[4][100];
  __shared__ float nl[4][100];
  int tid = threadIdx.x, rt = blockIdx.x * 4, dir = blockIdx.y;
  const float* src = a.wt + dir * 30000;
  for (int i = tid; i < 30000; i += 256) WT[i] = src[i];
  for (int i = tid; i < 400; i += 256) hl[i / 100][i % 100] = 0.f;
  __syncthreads();
  const float* bhh = a.bhh[dir];
  for (int t = 0; t < 40; ++t) {
    for (int it = tid; it < 400; it += 256) {
      int r = it / 100, j = it - r * 100, row = rt + r;
      float v = 0.f;
      if (row < BM1) {
        float hr = bhh[j], hz = bhh[100 + j], hn = bhh[200 + j];
        const float* w0 = WT + j;
        const float* hrow = hl[r];
        for (int k = 0; k < 100; ++k) {
          float hv = hrow[k];
          hr += hv * w0[k * 100];
          hz += hv * w0[10000 + k * 100];
          hn += hv * w0[20000 + k * 100];
        }
        size_t xb = (((size_t)dir * 40 + t) * BM1 + row) * 300;
        float xr = a.xg[xb + j], xz = a.xg[xb + 100 + j], xn = a.xg[xb + 200 + j];
        float rg = sigm(xr + hr), zg = sigm(xz + hz);
        float ng = tanhf(xn + rg * hn);
        v = (1.f - zg) * ng + zg * hl[r][j];
        int tin = dir ? (39 - t) : t;
        size_t ot = ((size_t)tin * BM1 + row) * 100 + j;
        (dir ? a.memb : a.memf)[ot] = v;
      }
      nl[r][j] = v;
    }
    __syncthreads();
    for (int it = tid; it < 400; it += 256) hl[it / 100][it % 100] = nl[it / 100][it % 100];
    __syncthreads();
  }
}

// mem = bt + mem_f + mem_b
__global__ void memcomb(const float* __restrict__ memf, const float* __restrict__ memb,
                        const float* __restrict__ sutt, float* __restrict__ memm) {
  int idx = blockIdx.x * 256 + threadIdx.x;
  if (idx >= 40 * BM1 * 100) return;
  int j = idx % 100; int rem = idx / 100; int row = rem % BM1; int t = rem / BM1;
  float v = memf[idx] + memb[idx];
  int sidx = row + 1 - 40 + t;
  if (sidx >= 0) v += sutt[sidx * 100 + j];
  memm[idx] = v;
}

__global__ void epsinit(const float* __restrict__ sutt, float* __restrict__ eps) {
  int idx = blockIdx.x * 256 + threadIdx.x;
  if (idx < BM1 * 100) eps[idx] = sutt[idx + 100];
}

// attention scores + softmax -> gates + attn output (f32)
__global__ __launch_bounds__(64) void attnsc(const float* __restrict__ eps,
                                             const float* __restrict__ memm,
                                             float* __restrict__ gatesw,
                                             float* __restrict__ outat) {
  int row = blockIdx.x, k = threadIdx.x;
  __shared__ float el[100];
  for (int i = k; i < 100; i += 64) el[i] = eps[row * 100 + i];
  __syncthreads();
  float val = -INFINITY;
  if (k < 40) {
    if (row + 1 - 40 + k >= 0) {
      const float* mrow = memm + ((size_t)k * BM1 + row) * 100;
      float s = 0.f;
      for (int d = 0; d < 100; ++d) s += el[d] * mrow[d];
      val = s;
    } else val = -1e10f;
  }
  float mx = val;
  for (int off = 32; off > 0; off >>= 1) mx = fmaxf(mx, __shfl_xor(mx, off));
  float ex = (k < 40) ? expf(val - mx) : 0.f;
  float sm = ex;
  for (int off = 32; off > 0; off >>= 1) sm += __shfl_xor(sm, off);
  if (k < 40) {
    float sc = ex / sm;
    gatesw[k * BM1 + row] = sc;
    outat[row * 40 + k] = sc;
  }
}

// cr/cw precompute GEMM: grid (16, 40, 2)
__global__ __launch_bounds__(256) void crcw3(const float* __restrict__ memm,
                                             const float* __restrict__ Wr, const float* __restrict__ br,
                                             const float* __restrict__ Ww, const float* __restrict__ bw,
                                             float* __restrict__ crb, float* __restrict__ cwb) {
  __shared__ float ml[32][101];
  int tid = threadIdx.x;
  int rt = blockIdx.x * 32, t = blockIdx.y, which = blockIdx.z;
  for (int idx = tid; idx < 3200; idx += 256) {
    int r = idx / 100, k = idx - r * 100; int row = rt + r;
    ml[r][k] = (row < BM1) ? memm[((size_t)t * BM1 + row) * 100 + k] : 0.f;
  }
  __syncthreads();
  const float* Wm = which ? Ww : Wr;
  const float* bm = which ? bw : br;
  float* ob = which ? cwb : crb;
  for (int o = tid; o < 3200; o += 256) {
    int r = o & 31, hh = o >> 5;
    float acc = bm[hh];
    const float* wr = Wm + hh * 100;
    for (int k = 0; k < 100; ++k) acc += ml[r][k] * wr[k];
    int row = rt + r;
    if (row < BM1) ob[((size_t)t * BM1 + row) * 100 + hh] = acc;
  }
}

// ------------------------------------------------------------------
// AttnGRU scan v3: block = 2 rows, grid 256; UrT/UT (k-major) in LDS.
// ------------------------------------------------------------------
struct Att3Args {
  const float* urT; const float* uT;   // k-major 10000 each
  const float* bur; const float* bu;
  const float* crb; const float* cwb;
  const float* gatesw; float* eps;
};

__global__ __launch_bounds__(256) void attscan3(Att3Args a) {
  __shared__ float UrT[10000];
  __shared__ float UT[10000];
  __shared__ float hl[2][100];
  __shared__ float nl[2][100];
  int tid = threadIdx.x, rt = blockIdx.x * 2;
  for (int i = tid; i < 10000; i += 256) { UrT[i] = a.urT[i]; UT[i] = a.uT[i]; }
  for (int i = tid; i < 200; i += 256) hl[i / 100][i % 100] = 0.f;
  __syncthreads();
  for (int t = 0; t < 40; ++t) {
    for (int it = tid; it < 200; it += 256) {
      int r = it / 100, j = it - r * 100, row = rt + r;
      float v = 0.f;
      if (row < BM1) {
        float hr = a.bur[j], hu = a.bu[j];
        const float* hrow = hl[r];
        for (int k = 0; k < 100; ++k) {
          float hv = hrow[k];
          hr += hv * UrT[k * 100 + j];
          hu += hv * UT[k * 100 + j];
        }
        size_t ix = ((size_t)t * BM1 + row) * 100 + j;
        float g = a.gatesw[t * BM1 + row];
        float rg = sigm(a.crb[ix] + hr);
        float ht = tanhf(a.cwb[ix] + rg * hu);
        v = g * ht + (1.f - g) * hl[r][j];
      }
      nl[r][j] = v;
    }
    __syncthreads();
    for (int it = tid; it < 200; it += 256) hl[it / 100][it % 100] = nl[it / 100][it % 100];
    __syncthreads();
  }
  for (int it = tid; it < 200; it += 256) {
    int r = it / 100, j = it - r * 100, row = rt + r;
    if (row < BM1) a.eps[row * 100 + j] += hl[r][j];
  }
}

// classifier -> f32
__global__ __launch_bounds__(64) void cls_k(const float* __restrict__ sutt,
                                            const float* __restrict__ eps,
                                            const float* __restrict__ cW, const float* __restrict__ cb,
                                            float* __restrict__ outp) {
  int b = blockIdx.x, j = threadIdx.x;
  __shared__ float sl[100];
  for (int i = j; i < 100; i += 64) sl[i] = (b == 0) ? sutt[i] : eps[(b - 1) * 100 + i];
  __syncthreads();
  float lg = -INFINITY;
  if (j < 7) {
    lg = cb[j];
    const float* wr = cW + j * 100;
    for (int k = 0; k < 100; ++k) lg += sl[k] * wr[k];
  }
  float mx = lg;
  for (int off = 32; off > 0; off >>= 1) mx = fmaxf(mx, __shfl_xor(mx, off));
  float ex = (j < 7) ? expf(lg - mx) : 0.f;
  float sm = ex;
  for (int off = 32; off > 0; off >>= 1) sm += __shfl_xor(sm, off);
  if (j < 7) outp[b * 7 + j] = lg - mx - logf(sm);
}

// ------------------------------------------------------------------
extern "C" void kernel_launch(void* const* d_in, const int* in_sizes, int n_in,
                              void* d_out, int out_size, void* d_ws, size_t ws_size,
                              hipStream_t stream) {
  (void)n_in; (void)out_size; (void)ws_size;

  bool sigOrder = (in_sizes[7] == 360000);   // r4 evidence: dict order

  const void *p_sents, *p_lens, *p_emb;
  const void *p_lWih_f, *p_lWhh_f, *p_lbih_f, *p_lbhh_f;
  const void *p_lWih_b, *p_lWhh_b, *p_lbih_b, *p_lbhh_b;
  const void *p_gWih_f, *p_gWhh_f, *p_gbih_f, *p_gbhh_f;
  const void *p_gWih_b, *p_gWhh_b, *p_gbih_b, *p_gbhh_b;
  const void *p_lin1W, *p_lin1b;
  const void *p_attWr, *p_attUr, *p_attW, *p_attU;
  const void *p_attbr, *p_attbur, *p_attbw, *p_attbu;
  const void *p_clsW, *p_clsb;

  p_sents = d_in[0]; p_lens = d_in[1]; p_emb = d_in[2];
  p_lWih_f = d_in[3]; p_lWhh_f = d_in[4]; p_lbih_f = d_in[5]; p_lbhh_f = d_in[6];
  if (sigOrder) {
    p_lWih_b = d_in[7];  p_lWhh_b = d_in[8];  p_lbih_b = d_in[9];  p_lbhh_b = d_in[10];
    p_lin1W  = d_in[11]; p_lin1b  = d_in[12];
    p_gWih_f = d_in[13]; p_gWhh_f = d_in[14]; p_gbih_f = d_in[15]; p_gbhh_f = d_in[16];
    p_gWih_b = d_in[17]; p_gWhh_b = d_in[18]; p_gbih_b = d_in[19]; p_gbhh_b = d_in[20];
    p_attWr  = d_in[21]; p_attbr  = d_in[22]; p_attUr  = d_in[23]; p_attbur = d_in[24];
    p_attW   = d_in[25]; p_attbw  = d_in[26]; p_attU   = d_in[27]; p_attbu  = d_in[28];
    p_clsW   = d_in[29]; p_clsb   = d_in[30];
  } else {
    p_gWih_f = d_in[7];  p_gWhh_f = d_in[8];  p_gbih_f = d_in[9];  p_gbhh_f = d_in[10];
    p_lWih_b = d_in[11]; p_lWhh_b = d_in[12]; p_lbih_b = d_in[13]; p_lbhh_b = d_in[14];
    p_gWih_b = d_in[15]; p_gWhh_b = d_in[16]; p_gbih_b = d_in[17]; p_gbhh_b = d_in[18];
    p_lin1W  = d_in[19]; p_lin1b  = d_in[20];
    p_attWr  = d_in[21]; p_attUr  = d_in[22]; p_attW   = d_in[23]; p_attU   = d_in[24];
    p_attbr  = d_in[25]; p_attbur = d_in[26]; p_attbw  = d_in[27]; p_attbu  = d_in[28];
    p_clsW   = d_in[29]; p_clsb   = d_in[30];
  }

  char* wp = (char*)d_ws;
  auto carve = [&](size_t bytes) {
    char* p = wp;
    wp += (bytes + 255) & ~(size_t)255;
    return p;
  };
  int*   flag  = (int*)  carve(256);
  float* allf  = (float*)carve((size_t)NF_TOT * 4);
  float* wt    = (float*)carve((size_t)120000 * 4);
  float* hbuf  = (float*)carve((size_t)2 * 2 * B_SZ * H_LS * 4);
  float* cst   = (float*)carve((size_t)2 * B_SZ * H_LS * 4);
  float* maxb  = (float*)carve((size_t)B_SZ * 600 * 4);
  float* sutt  = (float*)carve((size_t)B_SZ * 100 * 4);
  float* xg    = (float*)carve((size_t)2 * 40 * BM1 * 300 * 4);
  float* memf  = (float*)carve((size_t)40 * BM1 * 100 * 4);
  float* memb  = (float*)carve((size_t)40 * BM1 * 100 * 4);
  float* memm  = (float*)carve((size_t)40 * BM1 * 100 * 4);
  float* gatesw= (float*)carve((size_t)40 * BM1 * 4);
  float* eps   = (float*)carve((size_t)BM1 * 100 * 4);
  // crb/cwb alias into xg (xg is dead after gru3; stream-ordered)
  float* crb   = xg;
  float* cwb   = xg + (size_t)40 * BM1 * 100;

  float* out_pred = (float*)d_out;
  float* out_attn = out_pred + (size_t)B_SZ * NC_;

  detect_k<<<1, 256, 0, stream>>>((const u32*)p_emb, flag);

  NormFArgs nf;
  {
    const void* srcs[NF_NSEG] = {
      p_lWih_f, p_lWhh_f, p_lWih_b, p_lWhh_b,
      p_lbih_f, p_lbhh_f, p_lbih_b, p_lbhh_b,
      p_gWih_f, p_gWhh_f, p_gbih_f, p_gbhh_f,
      p_gWih_b, p_gWhh_b, p_gbih_b, p_gbhh_b,
      p_lin1W,  p_lin1b,
      p_attWr,  p_attUr,  p_attW,   p_attU,
      p_attbr,  p_attbur, p_attbw,  p_attbu,
      p_clsW,   p_clsb };
    for (int i = 0; i < NF_NSEG; ++i) nf.src[i] = srcs[i];
    nf.flag = flag; nf.dst = allf;
  }
  norm_f32<<<2048, 256, 0, stream>>>(nf);
  transp_k<<<(120000 + 255) / 256, 256, 0, stream>>>(allf, wt);

  Lstm3Args la;
  la.sents = (const int*)p_sents; la.lens = (const int*)p_lens;
  la.emb = p_emb;
  la.Wih[0] = allf + AF_LWIH_F; la.Wih[1] = allf + AF_LWIH_B;
  la.Whh[0] = allf + AF_LWHH_F; la.Whh[1] = allf + AF_LWHH_B;
  la.bih[0] = allf + AF_LBIH_F; la.bih[1] = allf + AF_LBIH_B;
  la.bhh[0] = allf + AF_LBHH_F; la.bhh[1] = allf + AF_LBHH_B;
  la.flag = flag;
  la.h = hbuf; la.c = cst; la.maxb = maxb;
  for (int s = 0; s < S_LEN; ++s) {
    la.s = s;
    lstm3<<<dim3(16, 10, 2), 256, 0, stream>>>(la);
  }

  sutt_k<<<512, 128, 0, stream>>>(maxb, allf + AF_LIN1W, allf + AF_LIN1B, sutt);

  gxg3<<<dim3(16, 40, 2), 256, 0, stream>>>(sutt,
      allf + AF_GWIH_F, allf + AF_GBIH_F,
      allf + AF_GWIH_B, allf + AF_GBIH_B, xg);

  Gru3Args ga;
  ga.wt = wt;                      // gWhhT_f at 0, _b at 30000
  ga.bhh[0] = allf + AF_GBHH_F; ga.bhh[1] = allf + AF_GBHH_B;
  ga.xg = xg; ga.memf = memf; ga.memb = memb;
  gru3<<<dim3(128, 2), 256, 0, stream>>>(ga);

  memcomb<<<(40 * BM1 * 100 + 255) / 256, 256, 0, stream>>>(memf, memb, sutt, memm);
  epsinit<<<(BM1 * 100 + 255) / 256, 256, 0, stream>>>(sutt, eps);

  for (int hop = 0; hop < NHOP; ++hop) {
    attnsc<<<BM1, 64, 0, stream>>>(eps, memm, gatesw, out_attn + (size_t)hop * BM1 * 40);
    crcw3<<<dim3(16, 40, 2), 256, 0, stream>>>(memm,
        allf + AF_ATTWR + hop * 10000, allf + AF_ATTBR + hop * 100,
        allf + AF_ATTW  + hop * 10000, allf + AF_ATTBW + hop * 100, crb, cwb);
    Att3Args aa;
    aa.urT = wt + 60000 + hop * 10000;
    aa.uT  = wt + 90000 + hop * 10000;
    aa.bur = allf + AF_ATTBUR + hop * 100;
    aa.bu  = allf + AF_ATTBU  + hop * 100;
    aa.crb = crb; aa.cwb = cwb;
    aa.gatesw = gatesw; aa.eps = eps;
    attscan3<<<256, 256, 0, stream>>>(aa);
  }

  cls_k<<<512, 64, 0, stream>>>(sutt, eps, allf + AF_CLSW, allf + AF_CLSB, out_pred);
}